// Round 1
// baseline (3649.636 us; speedup 1.0000x reference)
//
#include <hip/hip_runtime.h>

#define H   27
#define H4  108
#define TT  78
#define NB  32768
#define LAYERS 3

__device__ __forceinline__ float fast_rcp(float x) { return __builtin_amdgcn_rcpf(x); }
__device__ __forceinline__ float fast_exp2(float x) { return __builtin_amdgcn_exp2f(x); }

// act(a) = s0 + s2 * 1/(1 + 2^(e1*a)) ; sigmoid: (0,1,-log2e), tanh: (-1,2,-2log2e)
#define LOG2E 1.4426950408889634f

// block = 256 threads = 4 waves; block covers 64 batch elements.
// wave w computes gate-type w (0:i 1:f 2:g 3:o) for all 64 elements -> weight
// addresses are wave-uniform -> s_load/SGPR broadcast operand in the FMA.
// grid = NB/64 = 512 blocks -> 2048 waves -> 2 waves/SIMD.
__launch_bounds__(256, 2)
__global__ void lstm3_fused(const float* __restrict__ x,
                            const float* __restrict__ h0,
                            const float* __restrict__ c0,
                            const float* __restrict__ Wih,
                            const float* __restrict__ Whh,
                            const float* __restrict__ bih,
                            const float* __restrict__ bhh,
                            const float* __restrict__ Wl,
                            const float* __restrict__ bl,
                            float* __restrict__ out)
{
    __shared__ float xbuf[H * 65];           // staged x_t, [k*65 + bi] (65: break staging bank conflict)
    __shared__ float hbuf[LAYERS][H * 64];   // h state per layer, [k*64 + bi] (stride 64: 2 lanes/bank = free)
    __shared__ float gbuf[H4 * 64];          // activated gates, [(gate*27+j)*64 + bi]
    __shared__ float obuf[H * 65];           // staged output

    const int tid   = threadIdx.x;
    const int w     = __builtin_amdgcn_readfirstlane(tid >> 6); // force uniform: gate type 0..3
    const int lane  = tid & 63;                                  // batch element within group
    const int bbase = blockIdx.x * 64;

    // activation constants for this wave (wave-uniform branch)
    const float e1 = (w == 2) ? (-2.f * LOG2E) : (-LOG2E);
    const float s2 = (w == 2) ?  2.f : 1.f;
    const float s0 = (w == 2) ? -1.f : 0.f;

    // c/h-update + linear-output j-range for this wave
    const int jbeg = w * 7;
    const int jcnt = (w == 3) ? 6 : 7;

    // ---- init: stage h0 -> hbuf (one-time; staging bank conflicts here are negligible) ----
    for (int e = tid; e < LAYERS * 64 * H; e += 256) {
        int l  = e / (64 * H);
        int r  = e - l * (64 * H);
        int bi = r / H;
        int k  = r - bi * H;
        hbuf[l][k * 64 + bi] = h0[(size_t)l * NB * H + (size_t)(bbase + bi) * H + k];
    }
    // c0 -> regs (one-time scattered loads, tiny)
    float c[LAYERS][7];
    #pragma unroll
    for (int l = 0; l < LAYERS; ++l) {
        #pragma unroll
        for (int jj = 0; jj < 7; ++jj) {
            int j = jbeg + jj;
            c[l][jj] = (jj < jcnt)
                     ? c0[(size_t)l * NB * H + (size_t)(bbase + lane) * H + j] : 0.f;
        }
    }
    __syncthreads();

    for (int t = 0; t < TT; ++t) {
        // ---- stage x_t cooperatively (coalesced 27-dword runs) ----
        for (int e = tid; e < 64 * H; e += 256) {
            int bi = e / H;
            int k  = e - bi * H;
            xbuf[k * 65 + bi] = x[((size_t)(bbase + bi) * TT + t) * H + k];
        }
        __syncthreads();

        #pragma unroll
        for (int l = 0; l < LAYERS; ++l) {
            // load this lane's input vector and h_prev into regs (conflict-free LDS reads)
            float xr[H], hr[H];
            const float* xin = (l == 0) ? xbuf : &hbuf[l - 1][0];
            const int    xs  = (l == 0) ? 65 : 64;
            #pragma unroll
            for (int k = 0; k < H; ++k) {
                xr[k] = xin[k * xs + lane];
                hr[k] = hbuf[l][k * 64 + lane];
            }

            const float* wi = Wih + ((size_t)l * H4 + w * H) * H;  // uniform -> s_load
            const float* wh = Whh + ((size_t)l * H4 + w * H) * H;
            const float* b1 = bih + l * H4 + w * H;
            const float* b2 = bhh + l * H4 + w * H;

            // 27 gate rows of this wave's gate type; 54 FMAs each, weights via SGPR
            #pragma unroll 2
            for (int jr = 0; jr < H; ++jr) {
                float a = b1[jr] + b2[jr];
                #pragma unroll
                for (int k = 0; k < H; ++k) a += wi[jr * H + k] * xr[k];
                #pragma unroll
                for (int k = 0; k < H; ++k) a += wh[jr * H + k] * hr[k];
                // activation: sigmoid (w!=2) or tanh (w==2)
                a = s0 + s2 * fast_rcp(1.f + fast_exp2(e1 * a));
                gbuf[(w * H + jr) * 64 + lane] = a;
            }
            __syncthreads();

            // c/h update for this wave's j-range
            #pragma unroll
            for (int jj = 0; jj < 7; ++jj) {
                if (jj < jcnt) {
                    int j = jbeg + jj;
                    float ig = gbuf[(0 * H + j) * 64 + lane];
                    float fg = gbuf[(1 * H + j) * 64 + lane];
                    float gg = gbuf[(2 * H + j) * 64 + lane];
                    float og = gbuf[(3 * H + j) * 64 + lane];
                    float cn = fg * c[l][jj] + ig * gg;
                    c[l][jj] = cn;
                    float th = -1.f + 2.f * fast_rcp(1.f + fast_exp2(-2.f * LOG2E * cn));
                    hbuf[l][j * 64 + lane] = og * th;
                }
            }
            __syncthreads();
        }

        // ---- final linear on layer-2 h ----
        {
            float h2[H];
            #pragma unroll
            for (int k = 0; k < H; ++k) h2[k] = hbuf[2][k * 64 + lane];
            #pragma unroll
            for (int jj = 0; jj < 7; ++jj) {
                if (jj < jcnt) {
                    int j = jbeg + jj;
                    float a = bl[j];
                    #pragma unroll
                    for (int k = 0; k < H; ++k) a += Wl[j * H + k] * h2[k];
                    obuf[j * 65 + lane] = a;
                }
            }
        }
        __syncthreads();

        // ---- cooperative coalesced store ----
        for (int e = tid; e < 64 * H; e += 256) {
            int bi = e / H;
            int k  = e - bi * H;
            out[((size_t)(bbase + bi) * TT + t) * H + k] = obuf[k * 65 + bi];
        }
        __syncthreads();  // protect obuf/xbuf before next timestep
    }
}

extern "C" void kernel_launch(void* const* d_in, const int* in_sizes, int n_in,
                              void* d_out, int out_size, void* d_ws, size_t ws_size,
                              hipStream_t stream) {
    (void)in_sizes; (void)n_in; (void)ws_size; (void)d_ws; (void)out_size;
    const float* x   = (const float*)d_in[0];
    const float* h0  = (const float*)d_in[1];
    const float* c0  = (const float*)d_in[2];
    const float* Wih = (const float*)d_in[3];
    const float* Whh = (const float*)d_in[4];
    const float* bih = (const float*)d_in[5];
    const float* bhh = (const float*)d_in[6];
    const float* Wl  = (const float*)d_in[7];
    const float* bl  = (const float*)d_in[8];
    float* out = (float*)d_out;

    lstm3_fused<<<dim3(NB / 64), dim3(256), 0, stream>>>(
        x, h0, c0, Wih, Whh, bih, bhh, Wl, bl, out);
}